// Round 4
// baseline (129.564 us; speedup 1.0000x reference)
//
#include <hip/hip_runtime.h>
#include <math.h>

#define B_N 4096
#define L_N 16
#define NJC 32            // j-chunks (grid.y)
#define ITI 64            // i's per block (one wave-width)
#define NW  4             // waves per block; each wave takes jc/NW j's
#define CSTRIDE 48        // floats per j record: [0:16)=A [16:32)=B [32:48)=C

#define NHALF_LOG2E 0.7213475204444817f   // 0.5 * log2(e)
#define LOG2E_F     1.4426950408889634f
#define LN2_F       0.6931471805599453f
#define LOG_2PI_F   1.8378770664093453f

typedef float f32x2 __attribute__((ext_vector_type(2)));

// ws layout (floats):
//   coef:     [B_N][CSTRIDE]   (768 KB, L2-resident)
//   partials: [NJC][17][B_N]   fields 0..15 = per-l exp2 sums, 16 = sum2

// ---- coefficients: logq2(i,j,l) = A*z^2 + B*z + C (log2 domain); also zero out ----
extern "C" __global__ __launch_bounds__(256)
void btc_coef(const float* __restrict__ zm, const float* __restrict__ zlv,
              float* __restrict__ coef, float* __restrict__ out) {
    const int g = blockIdx.x * 256 + threadIdx.x;   // 65536 = B_N * L_N
    if (g == 0) out[0] = 0.0f;                      // atomic target for btc_reduce
    const int j = g >> 4, l = g & 15;
    float M  = zm[g];
    float lv = zlv[g];
    float A  = -NHALF_LOG2E * __builtin_amdgcn_exp2f(-LOG2E_F * lv);
    float Bc = -2.0f * A * M;
    float C  = fmaf(A, M * M, -NHALF_LOG2E * (lv + LOG_2PI_F));
    float* r = coef + (size_t)j * CSTRIDE;
    r[l] = A; r[16 + l] = Bc; r[32 + l] = C;
}

// ---- main: 4 waves share 64 i's, split the j-chunk; coefficients via s_load ----
extern "C" __global__ __launch_bounds__(256, 8)
void btc_main(const float* __restrict__ z, const float* __restrict__ coef,
              float* __restrict__ part, int jc /* j's per chunk, mult of NW */) {
    __shared__ float red[NW][17][ITI];

    const int tid  = threadIdx.x;
    const int lane = tid & 63;
    const int w    = tid >> 6;
    const int i    = blockIdx.x * ITI + lane;
    const int jpw  = jc / NW;
    const int jb   = blockIdx.y * jc + w * jpw;     // this wave's j-range

    f32x2 z2[8], u2[8], acc2[8];
    {
        const float4* zr = (const float4*)(z + (size_t)i * L_N);
        #pragma unroll
        for (int q = 0; q < 4; ++q) {
            float4 v = zr[q];
            z2[2*q]   = (f32x2){v.x, v.y};
            z2[2*q+1] = (f32x2){v.z, v.w};
        }
    }
    #pragma unroll
    for (int q = 0; q < 8; ++q) { u2[q] = z2[q] * z2[q]; acc2[q] = (f32x2){0.0f, 0.0f}; }
    float sum2 = 0.0f;   // sum_j exp2(sum_l logq2); diagonal term keeps the total > 0

    const float* cj = coef + (size_t)jb * CSTRIDE;
    for (int jj = 0; jj < jpw; ++jj, cj += CSTRIDE) {
        f32x2 sva = {0.0f, 0.0f}, svb = {0.0f, 0.0f};
        #pragma unroll
        for (int q = 0; q < 8; ++q) {
            // cj is wave-uniform -> these become s_load_dwordx16 batches
            f32x2 A  = {cj[2*q],      cj[2*q + 1]};
            f32x2 Bc = {cj[16 + 2*q], cj[16 + 2*q + 1]};
            f32x2 C  = {cj[32 + 2*q], cj[32 + 2*q + 1]};
            f32x2 t  = Bc * z2[q];          // v_pk_mul_f32
            t        = A * u2[q] + t;       // v_pk_fma_f32
            f32x2 lg = t + C;               // v_pk_add_f32
            if (q & 1) svb += lg; else sva += lg;
            f32x2 e;
            e.x = __builtin_amdgcn_exp2f(lg.x);
            e.y = __builtin_amdgcn_exp2f(lg.y);
            acc2[q] += e;
        }
        f32x2 sv = sva + svb;
        sum2 += __builtin_amdgcn_exp2f(sv.x + sv.y);
    }

    // cross-wave combine in LDS (only LDS use in this kernel)
    #pragma unroll
    for (int q = 0; q < 8; ++q) {
        red[w][2*q][lane]     = acc2[q].x;
        red[w][2*q + 1][lane] = acc2[q].y;
    }
    red[w][16][lane] = sum2;
    __syncthreads();
    if (w == 0) {
        float* base = part + (size_t)blockIdx.y * 17 * B_N + blockIdx.x * ITI + lane;
        #pragma unroll
        for (int f = 0; f < 17; ++f) {
            float v = (red[0][f][lane] + red[1][f][lane]) +
                      (red[2][f][lane] + red[3][f][lane]);
            base[(size_t)f * B_N] = v;
        }
    }
}

// ---- reduce chunks, finish per-i logs, global sum via one atomic ----
extern "C" __global__ __launch_bounds__(256)
void btc_reduce(const float* __restrict__ part, float* __restrict__ out, int njc) {
    const int tid = threadIdx.x;
    const int i   = blockIdx.x * 256 + tid;

    float accl[L_N];
    #pragma unroll
    for (int l = 0; l < L_N; ++l) accl[l] = 0.0f;
    float sum2 = 0.0f;

    for (int c = 0; c < njc; ++c) {
        const float* b = part + (size_t)c * 17 * B_N + i;
        #pragma unroll
        for (int l = 0; l < L_N; ++l) accl[l] += b[(size_t)l * B_N];
        sum2 += b[(size_t)16 * B_N];
    }

    float lqprod2 = 0.0f;
    #pragma unroll
    for (int l = 0; l < L_N; ++l) lqprod2 += __builtin_amdgcn_logf(accl[l]);
    float v = LN2_F * (__builtin_amdgcn_logf(sum2) - lqprod2);

    #pragma unroll
    for (int off = 32; off > 0; off >>= 1) v += __shfl_down(v, off);
    __shared__ float red[4];
    const int lane = tid & 63, w = tid >> 6;
    if (lane == 0) red[w] = v;
    __syncthreads();
    if (tid == 0)
        atomicAdd(out, ((red[0] + red[1]) + (red[2] + red[3])) * (1.0f / (float)B_N));
}

extern "C" void kernel_launch(void* const* d_in, const int* in_sizes, int n_in,
                              void* d_out, int out_size, void* d_ws, size_t ws_size,
                              hipStream_t stream) {
    const float* z   = (const float*)d_in[0];
    const float* zm  = (const float*)d_in[1];
    const float* zlv = (const float*)d_in[2];
    float* out  = (float*)d_out;
    float* coef = (float*)d_ws;
    float* part = coef + (size_t)B_N * CSTRIDE;

    int njc = NJC;
    while (njc > 1) {
        size_t need = ((size_t)B_N * CSTRIDE + (size_t)njc * 17 * B_N) * sizeof(float);
        if (need <= ws_size) break;
        njc >>= 1;
    }
    const int jc = B_N / njc;   // multiple of NW for njc <= 512

    hipLaunchKernelGGL(btc_coef, dim3(B_N * L_N / 256), dim3(256), 0, stream,
                       zm, zlv, coef, out);
    hipLaunchKernelGGL(btc_main, dim3(B_N / ITI, njc), dim3(256), 0, stream,
                       z, coef, part, jc);
    hipLaunchKernelGGL(btc_reduce, dim3(B_N / 256), dim3(256), 0, stream,
                       part, out, njc);
}

// Round 5
// 67.844 us; speedup vs baseline: 1.9097x; 1.9097x over previous
//
#include <hip/hip_runtime.h>
#include <math.h>

#define B_N 4096
#define L_N 16
#define NJC 32             // j-chunks (grid.y)
#define IPB 128            // i's per block: 64 lanes x 2 rows
#define NW  4              // waves per block; each takes JT/NW j's of the staged tile
#define JT  128            // j's per staged LDS tile
#define JPW (JT / NW)      // 32

#define NHALF_LOG2E 0.7213475204444817f   // 0.5 * log2(e)
#define LOG2E_F     1.4426950408889634f
#define LN2_F       0.6931471805599453f
#define LOG_2PI_F   1.8378770664093453f

typedef float f32x2 __attribute__((ext_vector_type(2)));

// LDS: staging sA/sB/sC (3*2048 floats = 24 KB) aliased with the cross-wave
// combine buffer red[NW][17][IPB] (8704 floats = 34 KB). 34.8 KB/block ->
// 4 blocks/CU -> 16 waves/CU. Alias guarded by __syncthreads() after the loop.
#define RED_F (NW * 17 * IPB)

// ws layout (floats): partials [njc][17][B_N]  (0..15 per-l exp2 sums, 16 = sum2)

extern "C" __global__ __launch_bounds__(256, 4)
void btc_main(const float* __restrict__ z, const float* __restrict__ zm,
              const float* __restrict__ zlv, float* __restrict__ part,
              int jc /* j's per chunk, multiple of JT */) {
    __shared__ __align__(16) float lds[RED_F];
    float* sA = lds;                    // [JT*L_N]
    float* sB = lds + JT * L_N;
    float* sC = lds + 2 * JT * L_N;
    float (*red)[17][IPB] = (float (*)[17][IPB])lds;

    const int tid  = threadIdx.x;
    const int lane = tid & 63;
    const int w    = tid >> 6;

    // two sample rows per lane
    f32x2 za[8], zb[8], acca[8], accb[8];
    {
        const float4* zra = (const float4*)(z + (size_t)(blockIdx.x * IPB + lane) * L_N);
        const float4* zrb = (const float4*)(z + (size_t)(blockIdx.x * IPB + 64 + lane) * L_N);
        #pragma unroll
        for (int q = 0; q < 4; ++q) {
            float4 va = zra[q], vb = zrb[q];
            za[2*q]   = (f32x2){va.x, va.y};  za[2*q+1] = (f32x2){va.z, va.w};
            zb[2*q]   = (f32x2){vb.x, vb.y};  zb[2*q+1] = (f32x2){vb.z, vb.w};
        }
    }
    #pragma unroll
    for (int q = 0; q < 8; ++q) { acca[q] = (f32x2){0.f, 0.f}; accb[q] = (f32x2){0.f, 0.f}; }
    float sum2a = 0.0f, sum2b = 0.0f;   // diag term keeps these > 0; no max tracking needed

    for (int t = 0; t < jc / JT; ++t) {
        __syncthreads();   // previous tile fully consumed
        // stage + transform 128 j's: 2048 elems/array, 2 float4 per thread, coalesced
        const size_t gbase = ((size_t)blockIdx.y * jc + (size_t)t * JT) * L_N;
        for (int e4 = tid * 4; e4 < JT * L_N; e4 += 1024) {
            float4 m4 = *(const float4*)(zm  + gbase + e4);
            float4 v4 = *(const float4*)(zlv + gbase + e4);
            float4 a4, b4, c4;
            float A;
            A = -NHALF_LOG2E * __builtin_amdgcn_exp2f(-LOG2E_F * v4.x);
            a4.x = A; b4.x = -2.0f * A * m4.x;
            c4.x = fmaf(A, m4.x * m4.x, -NHALF_LOG2E * (v4.x + LOG_2PI_F));
            A = -NHALF_LOG2E * __builtin_amdgcn_exp2f(-LOG2E_F * v4.y);
            a4.y = A; b4.y = -2.0f * A * m4.y;
            c4.y = fmaf(A, m4.y * m4.y, -NHALF_LOG2E * (v4.y + LOG_2PI_F));
            A = -NHALF_LOG2E * __builtin_amdgcn_exp2f(-LOG2E_F * v4.z);
            a4.z = A; b4.z = -2.0f * A * m4.z;
            c4.z = fmaf(A, m4.z * m4.z, -NHALF_LOG2E * (v4.z + LOG_2PI_F));
            A = -NHALF_LOG2E * __builtin_amdgcn_exp2f(-LOG2E_F * v4.w);
            a4.w = A; b4.w = -2.0f * A * m4.w;
            c4.w = fmaf(A, m4.w * m4.w, -NHALF_LOG2E * (v4.w + LOG_2PI_F));
            *(float4*)&sA[e4] = a4;
            *(float4*)&sB[e4] = b4;
            *(float4*)&sC[e4] = c4;
        }
        __syncthreads();

        for (int jj = 0; jj < JPW; ++jj) {
            const int jo = (w * JPW + jj) * L_N;
            const float4* pA = (const float4*)&sA[jo];
            const float4* pB = (const float4*)&sB[jo];
            const float4* pC = (const float4*)&sC[jo];
            f32x2 s2a = {0.f, 0.f}, s2b = {0.f, 0.f};
            #pragma unroll
            for (int q = 0; q < 4; ++q) {
                float4 A4 = pA[q], B4 = pB[q], C4 = pC[q];   // uniform -> LDS broadcast
                f32x2 A0 = {A4.x, A4.y}, A1 = {A4.z, A4.w};
                f32x2 B0 = {B4.x, B4.y}, B1 = {B4.z, B4.w};
                f32x2 C0 = {C4.x, C4.y}, C1 = {C4.z, C4.w};
                f32x2 tv, lg;
                // row a
                tv = A0 * za[2*q] + B0;  lg = tv * za[2*q] + C0;  s2a += lg;
                acca[2*q]   += (f32x2){__builtin_amdgcn_exp2f(lg.x), __builtin_amdgcn_exp2f(lg.y)};
                tv = A1 * za[2*q+1] + B1; lg = tv * za[2*q+1] + C1; s2a += lg;
                acca[2*q+1] += (f32x2){__builtin_amdgcn_exp2f(lg.x), __builtin_amdgcn_exp2f(lg.y)};
                // row b
                tv = A0 * zb[2*q] + B0;  lg = tv * zb[2*q] + C0;  s2b += lg;
                accb[2*q]   += (f32x2){__builtin_amdgcn_exp2f(lg.x), __builtin_amdgcn_exp2f(lg.y)};
                tv = A1 * zb[2*q+1] + B1; lg = tv * zb[2*q+1] + C1; s2b += lg;
                accb[2*q+1] += (f32x2){__builtin_amdgcn_exp2f(lg.x), __builtin_amdgcn_exp2f(lg.y)};
            }
            sum2a += __builtin_amdgcn_exp2f(s2a.x + s2a.y);
            sum2b += __builtin_amdgcn_exp2f(s2b.x + s2b.y);
        }
    }

    __syncthreads();   // all waves done with staging buffers before alias reuse
    #pragma unroll
    for (int q = 0; q < 8; ++q) {
        red[w][2*q][lane]        = acca[q].x;
        red[w][2*q + 1][lane]    = acca[q].y;
        red[w][2*q][64 + lane]   = accb[q].x;
        red[w][2*q + 1][64 + lane] = accb[q].y;
    }
    red[w][16][lane]      = sum2a;
    red[w][16][64 + lane] = sum2b;
    __syncthreads();
    if (tid < IPB) {
        float* base = part + (size_t)blockIdx.y * 17 * B_N + blockIdx.x * IPB + tid;
        #pragma unroll
        for (int f = 0; f < 17; ++f) {
            float v = (red[0][f][tid] + red[1][f][tid]) +
                      (red[2][f][tid] + red[3][f][tid]);
            base[(size_t)f * B_N] = v;
        }
    }
}

// ---- reduce chunks, finish per-i logs, global sum via one atomic ----
extern "C" __global__ __launch_bounds__(256)
void btc_reduce(const float* __restrict__ part, float* __restrict__ out, int njc) {
    const int tid = threadIdx.x;
    const int i   = blockIdx.x * 256 + tid;

    float accl[L_N];
    #pragma unroll
    for (int l = 0; l < L_N; ++l) accl[l] = 0.0f;
    float sum2 = 0.0f;

    for (int c = 0; c < njc; ++c) {
        const float* b = part + (size_t)c * 17 * B_N + i;
        #pragma unroll
        for (int l = 0; l < L_N; ++l) accl[l] += b[(size_t)l * B_N];
        sum2 += b[(size_t)16 * B_N];
    }

    float lqprod2 = 0.0f;
    #pragma unroll
    for (int l = 0; l < L_N; ++l) lqprod2 += __builtin_amdgcn_logf(accl[l]);
    float v = LN2_F * (__builtin_amdgcn_logf(sum2) - lqprod2);

    #pragma unroll
    for (int off = 32; off > 0; off >>= 1) v += __shfl_down(v, off);
    __shared__ float red[4];
    const int lane = tid & 63, w = tid >> 6;
    if (lane == 0) red[w] = v;
    __syncthreads();
    if (tid == 0)
        atomicAdd(out, ((red[0] + red[1]) + (red[2] + red[3])) * (1.0f / (float)B_N));
}

extern "C" void kernel_launch(void* const* d_in, const int* in_sizes, int n_in,
                              void* d_out, int out_size, void* d_ws, size_t ws_size,
                              hipStream_t stream) {
    const float* z   = (const float*)d_in[0];
    const float* zm  = (const float*)d_in[1];
    const float* zlv = (const float*)d_in[2];
    float* out  = (float*)d_out;
    float* part = (float*)d_ws;

    int njc = NJC;
    while (njc > 1) {
        size_t need = (size_t)njc * 17 * B_N * sizeof(float);
        if (need <= ws_size) break;
        njc >>= 1;
    }
    const int jc = B_N / njc;   // >= 128, multiple of JT

    hipMemsetAsync(out, 0, sizeof(float), stream);
    hipLaunchKernelGGL(btc_main, dim3(B_N / IPB, njc), dim3(256), 0, stream,
                       z, zm, zlv, part, jc);
    hipLaunchKernelGGL(btc_reduce, dim3(B_N / 256), dim3(256), 0, stream,
                       part, out, njc);
}

// Round 6
// 53.602 us; speedup vs baseline: 2.4171x; 1.2657x over previous
//
#include <hip/hip_runtime.h>
#include <math.h>

#define B_N 4096
#define L_N 16
#define NJC 32             // j-chunks (grid.y)
#define R_I 4              // sample rows per lane
#define IPB 256            // i's per block: 64 lanes x R_I rows
#define NW  4              // waves per block; each takes JT/NW j's of the staged tile
#define JT  128            // j's per staged LDS tile
#define JPW (JT / NW)      // 32

#define NHALF_LOG2E 0.7213475204444817f   // 0.5 * log2(e)
#define LOG2E_F     1.4426950408889634f
#define LN2_F       0.6931471805599453f
#define LOG_2PI_F   1.8378770664093453f

typedef float f32x2 __attribute__((ext_vector_type(2)));

// LDS: staging sA/sB/sC (3*2048 floats = 24 KB) aliased with the combine
// buffer red[NW][17][128] (34816 B). Syncs guard the alias.
#define LDSF (NW * 17 * 128)

// ws layout (floats):
//   part : [njc][17][B_N]   per-chunk partials (0..15 = per-l exp2 sums, 16 = sum2)
//   part2: [17][B_N]        chunk-summed

extern "C" __global__ __launch_bounds__(256, 2)
void btc_main(const float* __restrict__ z, const float* __restrict__ zm,
              const float* __restrict__ zlv, float* __restrict__ part,
              int jc /* j's per chunk, multiple of JT */) {
    __shared__ __align__(16) float lds[LDSF];
    float* sA = lds;                    // [JT*L_N]
    float* sB = lds + JT * L_N;
    float* sC = lds + 2 * JT * L_N;
    float (*red)[17][128] = (float (*)[17][128])lds;

    const int tid  = threadIdx.x;
    const int lane = tid & 63;
    const int w    = tid >> 6;

    // four sample rows per lane: i = blockIdx.x*IPB + r*64 + lane
    f32x2 zr[R_I][8], acc[R_I][8];
    float sum2[R_I];
    #pragma unroll
    for (int r = 0; r < R_I; ++r) {
        const float4* zp = (const float4*)(z + (size_t)(blockIdx.x * IPB + r * 64 + lane) * L_N);
        #pragma unroll
        for (int q = 0; q < 4; ++q) {
            float4 v = zp[q];
            zr[r][2*q]   = (f32x2){v.x, v.y};
            zr[r][2*q+1] = (f32x2){v.z, v.w};
            acc[r][2*q]   = (f32x2){0.f, 0.f};
            acc[r][2*q+1] = (f32x2){0.f, 0.f};
        }
        sum2[r] = 0.0f;   // diag term keeps this > 0; no max tracking needed
    }

    for (int t = 0; t < jc / JT; ++t) {
        __syncthreads();   // previous tile fully consumed
        const size_t gbase = ((size_t)blockIdx.y * jc + (size_t)t * JT) * L_N;
        for (int e4 = tid * 4; e4 < JT * L_N; e4 += 1024) {
            float4 m4 = *(const float4*)(zm  + gbase + e4);
            float4 v4 = *(const float4*)(zlv + gbase + e4);
            float4 a4, b4, c4;
            float A;
            A = -NHALF_LOG2E * __builtin_amdgcn_exp2f(-LOG2E_F * v4.x);
            a4.x = A; b4.x = -2.0f * A * m4.x;
            c4.x = fmaf(A, m4.x * m4.x, -NHALF_LOG2E * (v4.x + LOG_2PI_F));
            A = -NHALF_LOG2E * __builtin_amdgcn_exp2f(-LOG2E_F * v4.y);
            a4.y = A; b4.y = -2.0f * A * m4.y;
            c4.y = fmaf(A, m4.y * m4.y, -NHALF_LOG2E * (v4.y + LOG_2PI_F));
            A = -NHALF_LOG2E * __builtin_amdgcn_exp2f(-LOG2E_F * v4.z);
            a4.z = A; b4.z = -2.0f * A * m4.z;
            c4.z = fmaf(A, m4.z * m4.z, -NHALF_LOG2E * (v4.z + LOG_2PI_F));
            A = -NHALF_LOG2E * __builtin_amdgcn_exp2f(-LOG2E_F * v4.w);
            a4.w = A; b4.w = -2.0f * A * m4.w;
            c4.w = fmaf(A, m4.w * m4.w, -NHALF_LOG2E * (v4.w + LOG_2PI_F));
            *(float4*)&sA[e4] = a4;
            *(float4*)&sB[e4] = b4;
            *(float4*)&sC[e4] = c4;
        }
        __syncthreads();

        for (int jj = 0; jj < JPW; ++jj) {
            const int jo = (w * JPW + jj) * L_N;
            const float4* pA = (const float4*)&sA[jo];
            const float4* pB = (const float4*)&sB[jo];
            const float4* pC = (const float4*)&sC[jo];
            f32x2 s2[R_I];
            #pragma unroll
            for (int r = 0; r < R_I; ++r) s2[r] = (f32x2){0.f, 0.f};
            #pragma unroll
            for (int q = 0; q < 4; ++q) {
                float4 A4 = pA[q], B4 = pB[q], C4 = pC[q];   // uniform -> LDS broadcast
                f32x2 A0 = {A4.x, A4.y}, A1 = {A4.z, A4.w};
                f32x2 B0 = {B4.x, B4.y}, B1 = {B4.z, B4.w};
                f32x2 C0 = {C4.x, C4.y}, C1 = {C4.z, C4.w};
                #pragma unroll
                for (int r = 0; r < R_I; ++r) {
                    f32x2 tv, lg;
                    tv = A0 * zr[r][2*q] + B0;  lg = tv * zr[r][2*q] + C0;  s2[r] += lg;
                    acc[r][2*q]   += (f32x2){__builtin_amdgcn_exp2f(lg.x), __builtin_amdgcn_exp2f(lg.y)};
                    tv = A1 * zr[r][2*q+1] + B1; lg = tv * zr[r][2*q+1] + C1; s2[r] += lg;
                    acc[r][2*q+1] += (f32x2){__builtin_amdgcn_exp2f(lg.x), __builtin_amdgcn_exp2f(lg.y)};
                }
            }
            #pragma unroll
            for (int r = 0; r < R_I; ++r)
                sum2[r] += __builtin_amdgcn_exp2f(s2[r].x + s2[r].y);
        }
    }

    // combine: 2 passes of 128 i's (rows 2p, 2p+1), LDS aliased with staging
    float* bbase = part + (size_t)blockIdx.y * 17 * B_N + blockIdx.x * IPB;
    #pragma unroll
    for (int p = 0; p < 2; ++p) {
        __syncthreads();   // staging reads (p=0) / previous pass reads (p=1) done
        #pragma unroll
        for (int q = 0; q < 8; ++q) {
            red[w][2*q][lane]        = acc[2*p][q].x;
            red[w][2*q + 1][lane]    = acc[2*p][q].y;
            red[w][2*q][64 + lane]   = acc[2*p + 1][q].x;
            red[w][2*q + 1][64 + lane] = acc[2*p + 1][q].y;
        }
        red[w][16][lane]      = sum2[2*p];
        red[w][16][64 + lane] = sum2[2*p + 1];
        __syncthreads();
        if (tid < 128) {
            #pragma unroll
            for (int f = 0; f < 17; ++f) {
                float v = (red[0][f][tid] + red[1][f][tid]) +
                          (red[2][f][tid] + red[3][f][tid]);
                bbase[(size_t)f * B_N + p * 128 + tid] = v;
            }
        }
    }
}

// ---- sum partials over chunks (wide grid); also zeroes the output scalar ----
extern "C" __global__ __launch_bounds__(256)
void btc_sum(const float* __restrict__ part, float* __restrict__ part2,
             float* __restrict__ out, int njc) {
    const int g = blockIdx.x * 256 + threadIdx.x;   // 17*B_N elems
    if (g == 0) out[0] = 0.0f;
    float s = 0.0f;
    for (int c = 0; c < njc; ++c) s += part[(size_t)c * 17 * B_N + g];
    part2[g] = s;
}

// ---- finish per-i logs, global mean via one atomic per block ----
extern "C" __global__ __launch_bounds__(256)
void btc_fin(const float* __restrict__ part2, float* __restrict__ out) {
    const int tid = threadIdx.x;
    const int i   = blockIdx.x * 256 + tid;

    float lqprod2 = 0.0f;
    #pragma unroll
    for (int l = 0; l < L_N; ++l)
        lqprod2 += __builtin_amdgcn_logf(part2[(size_t)l * B_N + i]);
    float v = LN2_F * (__builtin_amdgcn_logf(part2[(size_t)16 * B_N + i]) - lqprod2);

    #pragma unroll
    for (int off = 32; off > 0; off >>= 1) v += __shfl_down(v, off);
    __shared__ float red[4];
    const int lane = tid & 63, w = tid >> 6;
    if (lane == 0) red[w] = v;
    __syncthreads();
    if (tid == 0)
        atomicAdd(out, ((red[0] + red[1]) + (red[2] + red[3])) * (1.0f / (float)B_N));
}

extern "C" void kernel_launch(void* const* d_in, const int* in_sizes, int n_in,
                              void* d_out, int out_size, void* d_ws, size_t ws_size,
                              hipStream_t stream) {
    const float* z   = (const float*)d_in[0];
    const float* zm  = (const float*)d_in[1];
    const float* zlv = (const float*)d_in[2];
    float* out  = (float*)d_out;
    float* part = (float*)d_ws;

    int njc = NJC;
    while (njc > 1) {
        size_t need = ((size_t)njc * 17 * B_N + 17 * B_N) * sizeof(float);
        if (need <= ws_size) break;
        njc >>= 1;
    }
    const int jc = B_N / njc;   // >= 128, multiple of JT
    float* part2 = part + (size_t)njc * 17 * B_N;

    hipLaunchKernelGGL(btc_main, dim3(B_N / IPB, njc), dim3(256), 0, stream,
                       z, zm, zlv, part, jc);
    hipLaunchKernelGGL(btc_sum, dim3(17 * B_N / 256), dim3(256), 0, stream,
                       part, part2, out, njc);
    hipLaunchKernelGGL(btc_fin, dim3(B_N / 256), dim3(256), 0, stream,
                       part2, out);
}